// Round 5
// baseline (1330.057 us; speedup 1.0000x reference)
//
#include <hip/hip_runtime.h>
#include <math.h>

#define B_ 8
#define S_ 1024
#define F_ 1024
#define FFN_ 4096
#define F2_ 2048
#define R_ 64
#define NSTEPS 6
#define EPS_ 1e-6f
#define LN_EPS_ 1e-5f

typedef unsigned short u16;
typedef __attribute__((ext_vector_type(8))) short bf16x8;
typedef __attribute__((ext_vector_type(8))) unsigned short u16x8;
typedef __attribute__((ext_vector_type(4))) float f32x4;

__device__ __forceinline__ u16 f2bf(float f) {
    union { float f; unsigned int u; } c; c.f = f;
    unsigned int r = c.u + 0x7FFF + ((c.u >> 16) & 1);
    return (u16)(r >> 16);
}
__device__ __forceinline__ float bf2f(u16 u) {
    union { unsigned int u; float f; } c; c.u = ((unsigned int)u) << 16;
    return c.f;
}

// ---------------- fp32 -> bf16 converter (8 elems/thread) ----------------
__global__ __launch_bounds__(256) void k_cvt_bf16(const float* __restrict__ in,
        u16* __restrict__ out, int n8) {
    int i = blockIdx.x * 256 + threadIdx.x;
    if (i >= n8) return;
    const float4* p = (const float4*)in + (size_t)i * 2;
    float4 a = p[0], b = p[1];
    u16x8 o;
    o[0] = f2bf(a.x); o[1] = f2bf(a.y); o[2] = f2bf(a.z); o[3] = f2bf(a.w);
    o[4] = f2bf(b.x); o[5] = f2bf(b.y); o[6] = f2bf(b.z); o[7] = f2bf(b.w);
    *((u16x8*)out + i) = o;
}

// ---------------- bf16 MFMA GEMM: C = A * B^T (+bias; opt. GELU+split) ----------------
// A: M x KD bf16 rm; Bw: N x KD bf16 rm. 128x128 tile, 4 waves 2x2 (m97 structure).
// GELUSPLIT: col<F2 -> obf (bf16 z1), col>=F2 -> obf2 (bf16 z2). else: of1 = fp32 out.
template<int KD, int NOUT, bool GELUSPLIT>
__global__ __launch_bounds__(256) void k_mfma_bt(
        const u16* __restrict__ A, const u16* __restrict__ Bw,
        const float* __restrict__ bias,
        u16* __restrict__ obf, u16* __restrict__ obf2, float* __restrict__ of1) {
    __shared__ u16 As[128 * 32];
    __shared__ u16 Bs[128 * 32];
    const int bm = blockIdx.x * 128;
    const int bn = blockIdx.y * 128;
    const int tid = threadIdx.x;
    const int wid = tid >> 6, lane = tid & 63;
    const int wr = wid >> 1, wc = wid & 1;
    const int lrow = lane & 15, lk = (lane >> 4) * 8;
    const int srow = lane >> 2, scol = (lane & 3) * 8;

    f32x4 acc[4][4] = {};

    const u16* Ag = A + (size_t)(bm + wid * 32) * KD;
    const u16* Bg = Bw + (size_t)(bn + wid * 32) * KD;

    for (int k0 = 0; k0 < KD; k0 += 32) {
        #pragma unroll
        for (int c = 0; c < 2; c++) {
            const u16* ga = Ag + (size_t)(c * 16 + srow) * KD + k0 + scol;
            u16* la = &As[(wid * 32 + c * 16) * 32];
            __builtin_amdgcn_global_load_lds(
                (const __attribute__((address_space(1))) void*)ga,
                (__attribute__((address_space(3))) void*)la, 16, 0, 0);
            const u16* gb = Bg + (size_t)(c * 16 + srow) * KD + k0 + scol;
            u16* lb = &Bs[(wid * 32 + c * 16) * 32];
            __builtin_amdgcn_global_load_lds(
                (const __attribute__((address_space(1))) void*)gb,
                (__attribute__((address_space(3))) void*)lb, 16, 0, 0);
        }
        __syncthreads();
        bf16x8 af[4], bfv[4];
        #pragma unroll
        for (int m = 0; m < 4; m++)
            af[m] = *(const bf16x8*)&As[(wr * 64 + m * 16 + lrow) * 32 + lk];
        #pragma unroll
        for (int n = 0; n < 4; n++)
            bfv[n] = *(const bf16x8*)&Bs[(wc * 64 + n * 16 + lrow) * 32 + lk];
        #pragma unroll
        for (int m = 0; m < 4; m++)
            #pragma unroll
            for (int n = 0; n < 4; n++)
                acc[m][n] = __builtin_amdgcn_mfma_f32_16x16x32_bf16(
                        af[m], bfv[n], acc[m][n], 0, 0, 0);
        __syncthreads();
    }

    const int crow = (lane >> 4) * 4;
    const int ccol = lane & 15;
    #pragma unroll
    for (int m = 0; m < 4; m++) {
        const int row = bm + wr * 64 + m * 16 + crow;
        #pragma unroll
        for (int n = 0; n < 4; n++) {
            const int col = bn + wc * 64 + n * 16 + ccol;
            const float bz = bias[col];
            #pragma unroll
            for (int r = 0; r < 4; r++) {
                float v = acc[m][n][r] + bz;
                if (GELUSPLIT) {
                    float g = 0.5f * v * (1.0f + erff(v * 0.7071067811865476f));
                    if (col < F2_) obf[(size_t)(row + r) * F2_ + col] = f2bf(g);
                    else           obf2[(size_t)(row + r) * F2_ + (col - F2_)] = f2bf(g);
                } else {
                    of1[(size_t)(row + r) * NOUT + col] = v;
                }
            }
        }
    }
}

// ---------------- fused: numer MFMA (blocks x<16) + fp32 Gram (blocks x>=16) ----------------
// numer: A (per-batch M x KD bf16 rm) * Bw (per-batch 64 x KD bf16 rm)^T, K-split 2,
//        out fp32 partial [ks][b][M][64].
// gram:  G[b] = Afp^T Afp, Afp per-batch AK x 64 fp32; 4 s-chunks of 16 cols.
template<int BM, int KD, int M, int AK>
__global__ __launch_bounds__(256) void k_numer_gram(
        const u16* __restrict__ A, const u16* __restrict__ Bw,
        float* __restrict__ outp,
        const float* __restrict__ Afp, float* __restrict__ G) {
    __shared__ u16 As[BM * 32];
    __shared__ u16 Bs[64 * 32];
    __shared__ float Agr[16][65];
    const int tid = threadIdx.x;
    const int b = blockIdx.z;

    if (blockIdx.x < 16) {
        // ---- numer role ----
        constexpr int MR = BM / 32;
        const int bm = blockIdx.x * BM;
        const int ks = blockIdx.y;
        const u16* Ab = A + (size_t)b * M * KD;
        const u16* Bb = Bw + (size_t)b * 64 * KD;
        const int wid = tid >> 6, lane = tid & 63;
        const int wr = wid >> 1, wc = wid & 1;
        const int lrow = lane & 15, lk = (lane >> 4) * 8;
        const int srow = lane >> 2, scol = (lane & 3) * 8;

        f32x4 acc[MR][2] = {};
        const int kbeg = ks * (KD / 2), kend = kbeg + KD / 2;

        for (int k0 = kbeg; k0 < kend; k0 += 32) {
            #pragma unroll
            for (int c = 0; c < BM / 64; c++) {
                const int rowb = c * 64 + wid * 16;
                const u16* ga = Ab + (size_t)(bm + rowb + srow) * KD + k0 + scol;
                u16* la = &As[rowb * 32];
                __builtin_amdgcn_global_load_lds(
                    (const __attribute__((address_space(1))) void*)ga,
                    (__attribute__((address_space(3))) void*)la, 16, 0, 0);
            }
            {
                const int rowb = wid * 16;
                const u16* gb = Bb + (size_t)(rowb + srow) * KD + k0 + scol;
                u16* lb = &Bs[rowb * 32];
                __builtin_amdgcn_global_load_lds(
                    (const __attribute__((address_space(1))) void*)gb,
                    (__attribute__((address_space(3))) void*)lb, 16, 0, 0);
            }
            __syncthreads();
            bf16x8 af[MR], bf2[2];
            #pragma unroll
            for (int m = 0; m < MR; m++)
                af[m] = *(const bf16x8*)&As[(wr * (BM / 2) + m * 16 + lrow) * 32 + lk];
            #pragma unroll
            for (int n = 0; n < 2; n++)
                bf2[n] = *(const bf16x8*)&Bs[(wc * 32 + n * 16 + lrow) * 32 + lk];
            #pragma unroll
            for (int m = 0; m < MR; m++)
                #pragma unroll
                for (int n = 0; n < 2; n++)
                    acc[m][n] = __builtin_amdgcn_mfma_f32_16x16x32_bf16(
                            af[m], bf2[n], acc[m][n], 0, 0, 0);
            __syncthreads();
        }

        const int crow = (lane >> 4) * 4;
        const int ccol = lane & 15;
        float* ob = outp + ((size_t)(ks * B_ + b) * M) * 64;
        #pragma unroll
        for (int m = 0; m < MR; m++) {
            const int row = bm + wr * (BM / 2) + m * 16 + crow;
            #pragma unroll
            for (int n = 0; n < 2; n++) {
                const int col = wc * 32 + n * 16 + ccol;
                #pragma unroll
                for (int r = 0; r < 4; r++)
                    ob[(size_t)(row + r) * 64 + col] = acc[m][n][r];
            }
        }
    } else {
        // ---- gram role: G[b][r][s], s in 16-col chunk ----
        const int schunk = (blockIdx.x - 16) * 2 + blockIdx.y;   // 0..3
        const int s0 = schunk * 16;
        const float* Ab = Afp + (size_t)b * AK * 64;
        const int r = tid & 63;
        const int sg = tid >> 6;       // 0..3
        float acc[4] = {};
        for (int k0 = 0; k0 < AK; k0 += 16) {
            #pragma unroll
            for (int i = 0; i < 4; i++) {
                const int idx = tid + i * 256;     // 0..1023
                Agr[idx >> 6][idx & 63] = Ab[(size_t)(k0 + (idx >> 6)) * 64 + (idx & 63)];
            }
            __syncthreads();
            #pragma unroll
            for (int kk = 0; kk < 16; kk++) {
                const float ar = Agr[kk][r];
                #pragma unroll
                for (int j = 0; j < 4; j++)
                    acc[j] = fmaf(ar, Agr[kk][s0 + sg * 4 + j], acc[j]);
            }
            __syncthreads();
        }
        float* Gb = G + (size_t)b * R_ * R_;
        #pragma unroll
        for (int j = 0; j < 4; j++)
            Gb[(size_t)r * R_ + s0 + sg * 4 + j] = acc[j];
    }
}

// ---------------- LayerNorm + ReLU: z2 bf16 -> xm_bf bf16 ----------------
__global__ __launch_bounds__(256) void k_ln_relu(const u16* __restrict__ z2bf,
        u16* __restrict__ xm_bf,
        const float* __restrict__ gamma, const float* __restrict__ beta) {
    const int row = blockIdx.x;  // 0..8191
    const u16* p = z2bf + (size_t)row * F2_;
    const int i0 = threadIdx.x * 8;
    u16x8 a = *(const u16x8*)(p + i0);
    float v[8];
    #pragma unroll
    for (int j = 0; j < 8; j++) v[j] = bf2f(a[j]);
    float s = 0.f, sq = 0.f;
    #pragma unroll
    for (int j = 0; j < 8; j++) { s += v[j]; sq += v[j] * v[j]; }
    __shared__ float red0[4], red1[4];
    #pragma unroll
    for (int off = 32; off > 0; off >>= 1) {
        s  += __shfl_down(s, off);
        sq += __shfl_down(sq, off);
    }
    const int wid = threadIdx.x >> 6, lane = threadIdx.x & 63;
    if (lane == 0) { red0[wid] = s; red1[wid] = sq; }
    __syncthreads();
    if (threadIdx.x == 0) {
        float S = red0[0] + red0[1] + red0[2] + red0[3];
        float SQ = red1[0] + red1[1] + red1[2] + red1[3];
        float mu = S * (1.0f / F2_);
        float var = SQ * (1.0f / F2_) - mu * mu;
        red0[0] = mu;
        red1[0] = rsqrtf(var + LN_EPS_);
    }
    __syncthreads();
    const float mu = red0[0], inv = red1[0];
    u16x8 o;
    #pragma unroll
    for (int j = 0; j < 8; j++) {
        float w = (v[j] - mu) * inv * gamma[i0 + j] + beta[i0 + j];
        o[j] = f2bf(w > 0.f ? w : 0.f);
    }
    *(u16x8*)&xm_bf[(size_t)row * F2_ + i0] = o;
}

// ---------------- bf16 transpose: in [b][d][n] -> out [b][n][d] ----------------
__global__ __launch_bounds__(256) void k_transpose_bf(const u16* __restrict__ in,
        u16* __restrict__ outp) {
    __shared__ u16 s[64][72];
    const int n0 = blockIdx.x * 64, d0 = blockIdx.y * 64, b = blockIdx.z;
    const u16* ib = in + (size_t)b * S_ * F2_;
    u16* ob = outp + (size_t)b * S_ * F2_;
    const int t = threadIdx.x;
    const int rr = t >> 3, cc = (t & 7) * 8;
    #pragma unroll
    for (int p = 0; p < 2; p++) {
        const int r = rr + p * 32;
        u16x8 v = *(const u16x8*)&ib[(size_t)(d0 + r) * F2_ + n0 + cc];
        #pragma unroll
        for (int j = 0; j < 8; j++) s[r][cc + j] = v[j];
    }
    __syncthreads();
    #pragma unroll
    for (int p = 0; p < 2; p++) {
        const int nr = rr + p * 32;
        u16x8 o;
        #pragma unroll
        for (int j = 0; j < 8; j++) o[j] = s[cc + j][nr];
        *(u16x8*)&ob[(size_t)(n0 + nr) * S_ + d0 + cc] = o;
    }
}

// ---------------- tile bases over batch (fp32 + bf16 transposed) ----------------
__global__ __launch_bounds__(256) void k_init_bases(const float* __restrict__ bases,
        float* __restrict__ bas, u16* __restrict__ basT) {
    const int i = blockIdx.x * 256 + threadIdx.x;  // over S*R = 65536
    const float v = bases[i];
    const int d = i >> 6, r = i & 63;
    const u16 vb = f2bf(v);
    #pragma unroll
    for (int b = 0; b < B_; b++) {
        bas[(size_t)b * S_ * R_ + i] = v;
        basT[(size_t)b * S_ * R_ + (size_t)r * S_ + d] = vb;
    }
}

// ---------------- softmax over r of 2 partials -> coef fp32 + coefT bf16 ----------------
__global__ __launch_bounds__(256) void k_softmax_coef(const float* __restrict__ ncp,
        float* __restrict__ coef, u16* __restrict__ coefT) {
    const size_t row = (size_t)blockIdx.x * 4 + (threadIdx.x >> 6);  // over B*F2 rows
    const int r = threadIdx.x & 63;
    const size_t CH = (size_t)B_ * F2_ * R_;
    float v = ncp[row * R_ + r] + ncp[CH + row * R_ + r];
    float m = v;
    #pragma unroll
    for (int off = 32; off > 0; off >>= 1) m = fmaxf(m, __shfl_xor(m, off));
    const float e = expf(v - m);
    float ssum = e;
    #pragma unroll
    for (int off = 32; off > 0; off >>= 1) ssum += __shfl_xor(ssum, off);
    const float cv = e / ssum;
    coef[row * R_ + r] = cv;
    const int b = (int)(row >> 11), n = (int)(row & 2047);
    coefT[((size_t)b * 64 + r) * F2_ + n] = f2bf(cv);
}

// ---------------- mult update: M = M * numer / (M @ G + eps); also bf16 M^T ----------------
__global__ __launch_bounds__(256) void k_mult_update(float* __restrict__ M_,
        const float* __restrict__ numer_p, const float* __restrict__ G,
        int NR, size_t CH, u16* __restrict__ Tout, int TK) {
    const int b = blockIdx.y;
    const int row = blockIdx.x * 4 + (threadIdx.x >> 6);
    const int r = threadIdx.x & 63;
    __shared__ float Gs[64][68];
    __shared__ float Ms[4][64];
    const float* Gb = G + (size_t)b * R_ * R_;
    for (int i = threadIdx.x; i < 64 * 64; i += 256) Gs[i >> 6][i & 63] = Gb[i];
    const size_t base = ((size_t)b * NR + row) * R_;
    Ms[threadIdx.x >> 6][r] = M_[base + r];
    __syncthreads();
    float acc = 0.f;
    const int lrow = threadIdx.x >> 6;
    #pragma unroll
    for (int s = 0; s < 64; s++) acc = fmaf(Ms[lrow][s], Gs[s][r], acc);
    const float num = numer_p[base + r] + numer_p[CH + base + r];
    const float nv = Ms[lrow][r] * num / (acc + EPS_);
    M_[base + r] = nv;
    Tout[((size_t)b * 64 + r) * TK + row] = f2bf(nv);
}

// ---------------- recon: z2r = bas @ coef^T; prod_bf = bf16(z1_bf * z2r) in place ----------------
__global__ __launch_bounds__(256) void k_recon_prod(const float* __restrict__ bas,
        const float* __restrict__ coef, u16* __restrict__ z1_bf) {
    const int d0 = blockIdx.x * 64;
    const int n0 = blockIdx.y * 64;
    const int b  = blockIdx.z;
    __shared__ float BasS[64][65], CoefS[64][65];
    const int tid = threadIdx.x, tx = tid & 15, ty = tid >> 4;
    {
        const int rr = tid & 63, q = tid >> 6;
        #pragma unroll
        for (int i = 0; i < 16; i++) {
            const int rowi = q * 16 + i;
            BasS[rowi][rr]  = bas[((size_t)b * S_ + d0 + rowi) * R_ + rr];
            CoefS[rowi][rr] = coef[((size_t)b * F2_ + n0 + rowi) * R_ + rr];
        }
    }
    __syncthreads();
    float acc[4][4] = {};
    #pragma unroll 8
    for (int r = 0; r < 64; r++) {
        float a[4], bb[4];
        #pragma unroll
        for (int i = 0; i < 4; i++) a[i] = BasS[ty * 4 + i][r];
        #pragma unroll
        for (int j = 0; j < 4; j++) bb[j] = CoefS[tx * 4 + j][r];
        #pragma unroll
        for (int i = 0; i < 4; i++)
            #pragma unroll
            for (int j = 0; j < 4; j++)
                acc[i][j] = fmaf(a[i], bb[j], acc[i][j]);
    }
    #pragma unroll
    for (int i = 0; i < 4; i++) {
        const size_t m = (size_t)b * S_ + d0 + ty * 4 + i;
        const size_t idx = m * F2_ + n0 + tx * 4;
        ushort4 zi = *(const ushort4*)&z1_bf[idx];
        ushort4 o;
        o.x = f2bf(bf2f(zi.x) * acc[i][0]);
        o.y = f2bf(bf2f(zi.y) * acc[i][1]);
        o.z = f2bf(bf2f(zi.z) * acc[i][2]);
        o.w = f2bf(bf2f(zi.w) * acc[i][3]);
        *(ushort4*)&z1_bf[idx] = o;
    }
}

extern "C" void kernel_launch(void* const* d_in, const int* in_sizes, int n_in,
                              void* d_out, int out_size, void* d_ws, size_t ws_size,
                              hipStream_t stream) {
    const float* x     = (const float*)d_in[0];
    const float* Wu    = (const float*)d_in[1];
    const float* bu    = (const float*)d_in[2];
    const float* gamma = (const float*)d_in[3];
    const float* beta  = (const float*)d_in[4];
    const float* Wv    = (const float*)d_in[5];
    const float* bv    = (const float*)d_in[6];
    const float* bases = (const float*)d_in[7];
    float* out = (float*)d_out;

    float* ws = (float*)d_ws;
    const size_t Z   = (size_t)B_ * S_ * F2_;          // 16,777,216
    const size_t NCR = (size_t)B_ * F2_ * R_;          // 1,048,576
    const size_t NBR = (size_t)B_ * S_ * R_;           // 524,288
    const size_t XBF = (size_t)B_ * S_ * F_;           // 8,388,608 u16
    const size_t WUBF = (size_t)FFN_ * F_;             // 4,194,304 u16

    // ---- block A (58.7 MB): [x_bf | Wu_bf | z2_bf], later re-used by [xmT | G | Wv_bf]
    u16*   x_bf   = (u16*)ws;
    u16*   Wu_bf  = x_bf + XBF;
    u16*   z2_bf  = Wu_bf + WUBF;          // Z u16; dead after ln_relu
    u16*   xmT_bf = (u16*)ws;              // alias [0..Z): written post-LN by transpose
    float* G      = (float*)((u16*)ws + Z);          // 8*64*64 floats (131 KB)
    u16*   Wv_bf  = (u16*)(G + (size_t)B_ * R_ * R_); // 4.2 MB, written at end
    // ---- persistent region after block A (block A = Z + XBF + WUBF u16 = 14,680,064 floats)
    float* p = ws + (Z + XBF + WUBF) / 2;
    u16*   z1_bf  = (u16*)p;               p += Z / 2;   // z1 / prod (bf16)
    u16*   xm_bf  = (u16*)p;               p += Z / 2;
    float* ncp    = p;                     p += 2 * NCR;
    float* nbp    = p;                     p += 2 * NBR;
    float* bas    = p;                     p += NBR;
    u16*   basT_bf = (u16*)p;              p += NBR / 2;
    float* coef   = p;                     p += NCR;
    u16*   coefT_bf = (u16*)p;             // + NCR/2

    // convert inputs to bf16
    k_cvt_bf16<<<dim3(4096), 256, 0, stream>>>(x,  x_bf,  (int)(XBF / 8));
    k_cvt_bf16<<<dim3(2048), 256, 0, stream>>>(Wu, Wu_bf, (int)(WUBF / 8));

    // front: gated MLP (bf16 MFMA) -> z1_bf + z2_bf
    k_mfma_bt<F_, F2_, true><<<dim3(64, 32), 256, 0, stream>>>(x_bf, Wu_bf, bu, z1_bf, z2_bf, nullptr);
    k_ln_relu<<<dim3(8192), 256, 0, stream>>>(z2_bf, xm_bf, gamma, beta);
    k_transpose_bf<<<dim3(32, 16, B_), 256, 0, stream>>>(xm_bf, xmT_bf);
    k_init_bases<<<dim3(256), 256, 0, stream>>>(bases, bas, basT_bf);

    // init: numer(xm^T bas0) + G(bas0) fused; softmax -> coef0
    k_numer_gram<128, S_, F2_, S_><<<dim3(18, 2, B_), 256, 0, stream>>>(xmT_bf, basT_bf, ncp, bas, G);
    k_softmax_coef<<<dim3(4096), 256, 0, stream>>>(ncp, coef, coefT_bf);

    // step 1: reference's numer/denom for coef are identical to init's (bas unchanged) -> reuse
    k_mult_update<<<dim3(512, B_), 256, 0, stream>>>(coef, ncp, G, F2_, NCR, coefT_bf, F2_);
    k_numer_gram<64, F2_, S_, F2_><<<dim3(18, 2, B_), 256, 0, stream>>>(xm_bf, coefT_bf, nbp, coef, G);
    k_mult_update<<<dim3(256, B_), 256, 0, stream>>>(bas, nbp, G, S_, NBR, basT_bf, S_);

    // steps 2..6
    for (int it = 1; it < NSTEPS; it++) {
        k_numer_gram<128, S_, F2_, S_><<<dim3(18, 2, B_), 256, 0, stream>>>(xmT_bf, basT_bf, ncp, bas, G);
        k_mult_update<<<dim3(512, B_), 256, 0, stream>>>(coef, ncp, G, F2_, NCR, coefT_bf, F2_);
        k_numer_gram<64, F2_, S_, F2_><<<dim3(18, 2, B_), 256, 0, stream>>>(xm_bf, coefT_bf, nbp, coef, G);
        k_mult_update<<<dim3(256, B_), 256, 0, stream>>>(bas, nbp, G, S_, NBR, basT_bf, S_);
    }

    // compute_coef (one more coef update with final bas)
    k_numer_gram<128, S_, F2_, S_><<<dim3(18, 2, B_), 256, 0, stream>>>(xmT_bf, basT_bf, ncp, bas, G);
    k_mult_update<<<dim3(512, B_), 256, 0, stream>>>(coef, ncp, G, F2_, NCR, coefT_bf, F2_);

    // reconstruction + gate, in place on z1_bf -> prod (bf16)
    k_recon_prod<<<dim3(16, 32, B_), 256, 0, stream>>>(bas, coef, z1_bf);

    // convert Wv (G dead now), then final projection (bf16 MFMA)
    k_cvt_bf16<<<dim3(1024), 256, 0, stream>>>(Wv, Wv_bf, (int)((size_t)F_ * F2_ / 8));
    k_mfma_bt<F2_, F_, false><<<dim3(64, 8), 256, 0, stream>>>(z1_bf, Wv_bf, bv, nullptr, nullptr, out);
}

// Round 6
// 774.772 us; speedup vs baseline: 1.7167x; 1.7167x over previous
//
#include <hip/hip_runtime.h>
#include <math.h>

#define B_ 8
#define S_ 1024
#define F_ 1024
#define FFN_ 4096
#define F2_ 2048
#define R_ 64
#define NSTEPS 6
#define EPS_ 1e-6f
#define LN_EPS_ 1e-5f

typedef unsigned short u16;
typedef __attribute__((ext_vector_type(8))) short bf16x8;
typedef __attribute__((ext_vector_type(8))) unsigned short u16x8;
typedef __attribute__((ext_vector_type(4))) float f32x4;

__device__ __forceinline__ u16 f2bf(float f) {
    union { float f; unsigned int u; } c; c.f = f;
    unsigned int r = c.u + 0x7FFF + ((c.u >> 16) & 1);
    return (u16)(r >> 16);
}
__device__ __forceinline__ float bf2f(u16 u) {
    union { unsigned int u; float f; } c; c.u = ((unsigned int)u) << 16;
    return c.f;
}

// ---------------- fp32 -> bf16 converter (8 elems/thread) ----------------
__global__ __launch_bounds__(256) void k_cvt_bf16(const float* __restrict__ in,
        u16* __restrict__ out, int n8) {
    int i = blockIdx.x * 256 + threadIdx.x;
    if (i >= n8) return;
    const float4* p = (const float4*)in + (size_t)i * 2;
    float4 a = p[0], b = p[1];
    u16x8 o;
    o[0] = f2bf(a.x); o[1] = f2bf(a.y); o[2] = f2bf(a.z); o[3] = f2bf(a.w);
    o[4] = f2bf(b.x); o[5] = f2bf(b.y); o[6] = f2bf(b.z); o[7] = f2bf(b.w);
    *((u16x8*)out + i) = o;
}

// ---------------- bf16 MFMA GEMM: C = A * B^T (+bias; opt. GELU+split) ----------------
// A: M x KD bf16 rm; Bw: N x KD bf16 rm. 128x128 tile, 4 waves 2x2 (m97 structure).
// GELUSPLIT: col<F2 -> obf (bf16 z1), col>=F2 -> obf2 (bf16 z2). else: of1 = fp32 out.
template<int KD, int NOUT, bool GELUSPLIT>
__global__ __launch_bounds__(256) void k_mfma_bt(
        const u16* __restrict__ A, const u16* __restrict__ Bw,
        const float* __restrict__ bias,
        u16* __restrict__ obf, u16* __restrict__ obf2, float* __restrict__ of1) {
    __shared__ u16 As[128 * 32];
    __shared__ u16 Bs[128 * 32];
    const int bm = blockIdx.x * 128;
    const int bn = blockIdx.y * 128;
    const int tid = threadIdx.x;
    const int wid = tid >> 6, lane = tid & 63;
    const int wr = wid >> 1, wc = wid & 1;
    const int lrow = lane & 15, lk = (lane >> 4) * 8;
    const int srow = lane >> 2, scol = (lane & 3) * 8;

    f32x4 acc[4][4] = {};

    const u16* Ag = A + (size_t)(bm + wid * 32) * KD;
    const u16* Bg = Bw + (size_t)(bn + wid * 32) * KD;

    for (int k0 = 0; k0 < KD; k0 += 32) {
        #pragma unroll
        for (int c = 0; c < 2; c++) {
            const u16* ga = Ag + (size_t)(c * 16 + srow) * KD + k0 + scol;
            u16* la = &As[(wid * 32 + c * 16) * 32];
            __builtin_amdgcn_global_load_lds(
                (const __attribute__((address_space(1))) void*)ga,
                (__attribute__((address_space(3))) void*)la, 16, 0, 0);
            const u16* gb = Bg + (size_t)(c * 16 + srow) * KD + k0 + scol;
            u16* lb = &Bs[(wid * 32 + c * 16) * 32];
            __builtin_amdgcn_global_load_lds(
                (const __attribute__((address_space(1))) void*)gb,
                (__attribute__((address_space(3))) void*)lb, 16, 0, 0);
        }
        __syncthreads();
        bf16x8 af[4], bfv[4];
        #pragma unroll
        for (int m = 0; m < 4; m++)
            af[m] = *(const bf16x8*)&As[(wr * 64 + m * 16 + lrow) * 32 + lk];
        #pragma unroll
        for (int n = 0; n < 4; n++)
            bfv[n] = *(const bf16x8*)&Bs[(wc * 64 + n * 16 + lrow) * 32 + lk];
        #pragma unroll
        for (int m = 0; m < 4; m++)
            #pragma unroll
            for (int n = 0; n < 4; n++)
                acc[m][n] = __builtin_amdgcn_mfma_f32_16x16x32_bf16(
                        af[m], bfv[n], acc[m][n], 0, 0, 0);
        __syncthreads();
    }

    const int crow = (lane >> 4) * 4;
    const int ccol = lane & 15;
    #pragma unroll
    for (int m = 0; m < 4; m++) {
        const int row = bm + wr * 64 + m * 16 + crow;
        #pragma unroll
        for (int n = 0; n < 4; n++) {
            const int col = bn + wc * 64 + n * 16 + ccol;
            const float bz = bias[col];
            #pragma unroll
            for (int r = 0; r < 4; r++) {
                float v = acc[m][n][r] + bz;
                if (GELUSPLIT) {
                    float g = 0.5f * v * (1.0f + erff(v * 0.7071067811865476f));
                    if (col < F2_) obf[(size_t)(row + r) * F2_ + col] = f2bf(g);
                    else           obf2[(size_t)(row + r) * F2_ + (col - F2_)] = f2bf(g);
                } else {
                    of1[(size_t)(row + r) * NOUT + col] = v;
                }
            }
        }
    }
}

// ---------------- small-N MFMA: P[ks] = A * B^T over K-chunk (N fixed = 64) ----------------
// A: M x KD bf16 rm (per batch), Bw: 64 x KD bf16 rm (per batch).
// out fp32 partial [ks][b][M][64]. grid (M/BM, KCH, B).
template<int BM, int KD, int KCH, int M>
__global__ __launch_bounds__(256) void k_nmf_bt(
        const u16* __restrict__ A, const u16* __restrict__ Bw,
        float* __restrict__ outp) {
    __shared__ u16 As[BM * 32];
    __shared__ u16 Bs[64 * 32];
    constexpr int MR = BM / 32;          // M-frags per wave (wave tile BM/2 x 32)
    const int bm = blockIdx.x * BM;
    const int ks = blockIdx.y;
    const int b  = blockIdx.z;
    const u16* Ab = A + (size_t)b * M * KD;
    const u16* Bb = Bw + (size_t)b * 64 * KD;
    const int tid = threadIdx.x;
    const int wid = tid >> 6, lane = tid & 63;
    const int wr = wid >> 1, wc = wid & 1;
    const int lrow = lane & 15, lk = (lane >> 4) * 8;
    const int srow = lane >> 2, scol = (lane & 3) * 8;

    f32x4 acc[MR][2] = {};
    const int kbeg = ks * (KD / KCH), kend = kbeg + KD / KCH;

    for (int k0 = kbeg; k0 < kend; k0 += 32) {
        #pragma unroll
        for (int c = 0; c < BM / 64; c++) {
            const int rowb = c * 64 + wid * 16;
            const u16* ga = Ab + (size_t)(bm + rowb + srow) * KD + k0 + scol;
            u16* la = &As[rowb * 32];
            __builtin_amdgcn_global_load_lds(
                (const __attribute__((address_space(1))) void*)ga,
                (__attribute__((address_space(3))) void*)la, 16, 0, 0);
        }
        {
            const int rowb = wid * 16;
            const u16* gb = Bb + (size_t)(rowb + srow) * KD + k0 + scol;
            u16* lb = &Bs[rowb * 32];
            __builtin_amdgcn_global_load_lds(
                (const __attribute__((address_space(1))) void*)gb,
                (__attribute__((address_space(3))) void*)lb, 16, 0, 0);
        }
        __syncthreads();
        bf16x8 af[MR], bf2[2];
        #pragma unroll
        for (int m = 0; m < MR; m++)
            af[m] = *(const bf16x8*)&As[(wr * (BM / 2) + m * 16 + lrow) * 32 + lk];
        #pragma unroll
        for (int n = 0; n < 2; n++)
            bf2[n] = *(const bf16x8*)&Bs[(wc * 32 + n * 16 + lrow) * 32 + lk];
        #pragma unroll
        for (int m = 0; m < MR; m++)
            #pragma unroll
            for (int n = 0; n < 2; n++)
                acc[m][n] = __builtin_amdgcn_mfma_f32_16x16x32_bf16(
                        af[m], bf2[n], acc[m][n], 0, 0, 0);
        __syncthreads();
    }

    const int crow = (lane >> 4) * 4;
    const int ccol = lane & 15;
    float* ob = outp + ((size_t)(ks * B_ + b) * M) * 64;
    #pragma unroll
    for (int m = 0; m < MR; m++) {
        const int row = bm + wr * (BM / 2) + m * 16 + crow;
        #pragma unroll
        for (int n = 0; n < 2; n++) {
            const int col = wc * 32 + n * 16 + ccol;
            #pragma unroll
            for (int r = 0; r < 4; r++)
                ob[(size_t)(row + r) * 64 + col] = acc[m][n][r];
        }
    }
}

// ---------------- LayerNorm + ReLU: z2 bf16 -> xm_bf bf16 ----------------
__global__ __launch_bounds__(256) void k_ln_relu(const u16* __restrict__ z2bf,
        u16* __restrict__ xm_bf,
        const float* __restrict__ gamma, const float* __restrict__ beta) {
    const int row = blockIdx.x;  // 0..8191
    const u16* p = z2bf + (size_t)row * F2_;
    const int i0 = threadIdx.x * 8;
    u16x8 a = *(const u16x8*)(p + i0);
    float v[8];
    #pragma unroll
    for (int j = 0; j < 8; j++) v[j] = bf2f(a[j]);
    float s = 0.f, sq = 0.f;
    #pragma unroll
    for (int j = 0; j < 8; j++) { s += v[j]; sq += v[j] * v[j]; }
    __shared__ float red0[4], red1[4];
    #pragma unroll
    for (int off = 32; off > 0; off >>= 1) {
        s  += __shfl_down(s, off);
        sq += __shfl_down(sq, off);
    }
    const int wid = threadIdx.x >> 6, lane = threadIdx.x & 63;
    if (lane == 0) { red0[wid] = s; red1[wid] = sq; }
    __syncthreads();
    if (threadIdx.x == 0) {
        float S = red0[0] + red0[1] + red0[2] + red0[3];
        float SQ = red1[0] + red1[1] + red1[2] + red1[3];
        float mu = S * (1.0f / F2_);
        float var = SQ * (1.0f / F2_) - mu * mu;
        red0[0] = mu;
        red1[0] = rsqrtf(var + LN_EPS_);
    }
    __syncthreads();
    const float mu = red0[0], inv = red1[0];
    u16x8 o;
    #pragma unroll
    for (int j = 0; j < 8; j++) {
        float w = (v[j] - mu) * inv * gamma[i0 + j] + beta[i0 + j];
        o[j] = f2bf(w > 0.f ? w : 0.f);
    }
    *(u16x8*)&xm_bf[(size_t)row * F2_ + i0] = o;
}

// ---------------- bf16 transpose: in [b][d][n] -> out [b][n][d] ----------------
__global__ __launch_bounds__(256) void k_transpose_bf(const u16* __restrict__ in,
        u16* __restrict__ outp) {
    __shared__ u16 s[64][72];
    const int n0 = blockIdx.x * 64, d0 = blockIdx.y * 64, b = blockIdx.z;
    const u16* ib = in + (size_t)b * S_ * F2_;
    u16* ob = outp + (size_t)b * S_ * F2_;
    const int t = threadIdx.x;
    const int rr = t >> 3, cc = (t & 7) * 8;
    #pragma unroll
    for (int p = 0; p < 2; p++) {
        const int r = rr + p * 32;
        u16x8 v = *(const u16x8*)&ib[(size_t)(d0 + r) * F2_ + n0 + cc];
        #pragma unroll
        for (int j = 0; j < 8; j++) s[r][cc + j] = v[j];
    }
    __syncthreads();
    #pragma unroll
    for (int p = 0; p < 2; p++) {
        const int nr = rr + p * 32;
        u16x8 o;
        #pragma unroll
        for (int j = 0; j < 8; j++) o[j] = s[cc + j][nr];
        *(u16x8*)&ob[(size_t)(n0 + nr) * S_ + d0 + cc] = o;
    }
}

// ---------------- tile bases over batch (fp32 + bf16 transposed) ----------------
__global__ __launch_bounds__(256) void k_init_bases(const float* __restrict__ bases,
        float* __restrict__ bas, u16* __restrict__ basT) {
    const int i = blockIdx.x * 256 + threadIdx.x;  // over S*R = 65536
    const float v = bases[i];
    const int d = i >> 6, r = i & 63;
    const u16 vb = f2bf(v);
    #pragma unroll
    for (int b = 0; b < B_; b++) {
        bas[(size_t)b * S_ * R_ + i] = v;
        basT[(size_t)b * S_ * R_ + (size_t)r * S_ + d] = vb;
    }
}

// ---------------- softmax over r of 4 partials -> coef fp32 + coefT bf16 ----------------
__global__ __launch_bounds__(256) void k_softmax_coef(const float* __restrict__ ncp,
        float* __restrict__ coef, u16* __restrict__ coefT) {
    const size_t row = (size_t)blockIdx.x * 4 + (threadIdx.x >> 6);  // over B*F2 rows
    const int r = threadIdx.x & 63;
    const size_t CH = (size_t)B_ * F2_ * R_;
    float v = 0.f;
    #pragma unroll
    for (int c = 0; c < 4; c++) v += ncp[c * CH + row * R_ + r];
    float m = v;
    #pragma unroll
    for (int off = 32; off > 0; off >>= 1) m = fmaxf(m, __shfl_xor(m, off));
    const float e = expf(v - m);
    float ssum = e;
    #pragma unroll
    for (int off = 32; off > 0; off >>= 1) ssum += __shfl_xor(ssum, off);
    const float cv = e / ssum;
    coef[row * R_ + r] = cv;
    const int b = (int)(row >> 11), n = (int)(row & 2047);
    coefT[((size_t)b * 64 + r) * F2_ + n] = f2bf(cv);
}

// ---------------- A^T A partial: Gp[b][ks][r][s], A is (K x 64) fp32 ----------------
__global__ __launch_bounds__(256) void k_ata_part(const float* __restrict__ A,
        float* __restrict__ Gp, int K) {
    const int ks = blockIdx.x;   // 16 k-chunks
    const int b  = blockIdx.y;
    const int chunk = K >> 4;
    const float* Ab = A + ((size_t)b * K + (size_t)ks * chunk) * R_;
    __shared__ float As[16][68];
    const int tid = threadIdx.x, tx = tid & 15, ty = tid >> 4;
    float acc[4][4] = {};
    for (int k0 = 0; k0 < chunk; k0 += 16) {
        const int rr = tid & 63, q = tid >> 6;
        #pragma unroll
        for (int i = 0; i < 4; i++) {
            const int kk = q * 4 + i;
            As[kk][rr] = Ab[(size_t)(k0 + kk) * R_ + rr];
        }
        __syncthreads();
        #pragma unroll
        for (int kk = 0; kk < 16; kk++) {
            float a[4], bb[4];
            #pragma unroll
            for (int i = 0; i < 4; i++) a[i] = As[kk][ty * 4 + i];
            #pragma unroll
            for (int j = 0; j < 4; j++) bb[j] = As[kk][tx * 4 + j];
            #pragma unroll
            for (int i = 0; i < 4; i++)
                #pragma unroll
                for (int j = 0; j < 4; j++)
                    acc[i][j] = fmaf(a[i], bb[j], acc[i][j]);
        }
        __syncthreads();
    }
    #pragma unroll
    for (int i = 0; i < 4; i++)
        #pragma unroll
        for (int j = 0; j < 4; j++)
            Gp[(((size_t)b * 16 + ks) * R_ + ty * 4 + i) * R_ + tx * 4 + j] = acc[i][j];
}

__global__ __launch_bounds__(256) void k_ata_reduce(const float* __restrict__ Gp,
        float* __restrict__ G) {
    const int idx = blockIdx.x * 256 + threadIdx.x;   // over B*64*64 = 32768
    const int b = idx >> 12, rs = idx & 4095;
    float s = 0.f;
    #pragma unroll
    for (int ks = 0; ks < 16; ks++) s += Gp[((size_t)b * 16 + ks) * 4096 + rs];
    G[idx] = s;
}

// ---------------- mult update: M = M * numer / (M @ G + eps); also bf16 M^T ----------------
__global__ __launch_bounds__(256) void k_mult_update(float* __restrict__ M_,
        const float* __restrict__ numer_p, const float* __restrict__ G,
        int NR, size_t CH, u16* __restrict__ Tout, int TK) {
    const int b = blockIdx.y;
    const int row = blockIdx.x * 4 + (threadIdx.x >> 6);
    const int r = threadIdx.x & 63;
    __shared__ float Gs[64][68];
    __shared__ float Ms[4][64];
    const float* Gb = G + (size_t)b * R_ * R_;
    for (int i = threadIdx.x; i < 64 * 64; i += 256) Gs[i >> 6][i & 63] = Gb[i];
    const size_t base = ((size_t)b * NR + row) * R_;
    Ms[threadIdx.x >> 6][r] = M_[base + r];
    __syncthreads();
    float acc = 0.f;
    const int lrow = threadIdx.x >> 6;
    #pragma unroll
    for (int s = 0; s < 64; s++) acc = fmaf(Ms[lrow][s], Gs[s][r], acc);
    float num = 0.f;
    #pragma unroll
    for (int c = 0; c < 4; c++) num += numer_p[c * CH + base + r];
    const float nv = Ms[lrow][r] * num / (acc + EPS_);
    M_[base + r] = nv;
    Tout[((size_t)b * 64 + r) * TK + row] = f2bf(nv);
}

// ---------------- recon: z2r = bas @ coef^T; prod_bf = bf16(z1_bf * z2r) in place ----------------
__global__ __launch_bounds__(256) void k_recon_prod(const float* __restrict__ bas,
        const float* __restrict__ coef, u16* __restrict__ z1_bf) {
    const int d0 = blockIdx.x * 64;
    const int n0 = blockIdx.y * 64;
    const int b  = blockIdx.z;
    __shared__ float BasS[64][65], CoefS[64][65];
    const int tid = threadIdx.x, tx = tid & 15, ty = tid >> 4;
    {
        const int rr = tid & 63, q = tid >> 6;
        #pragma unroll
        for (int i = 0; i < 16; i++) {
            const int rowi = q * 16 + i;
            BasS[rowi][rr]  = bas[((size_t)b * S_ + d0 + rowi) * R_ + rr];
            CoefS[rowi][rr] = coef[((size_t)b * F2_ + n0 + rowi) * R_ + rr];
        }
    }
    __syncthreads();
    float acc[4][4] = {};
    #pragma unroll 8
    for (int r = 0; r < 64; r++) {
        float a[4], bb[4];
        #pragma unroll
        for (int i = 0; i < 4; i++) a[i] = BasS[ty * 4 + i][r];
        #pragma unroll
        for (int j = 0; j < 4; j++) bb[j] = CoefS[tx * 4 + j][r];
        #pragma unroll
        for (int i = 0; i < 4; i++)
            #pragma unroll
            for (int j = 0; j < 4; j++)
                acc[i][j] = fmaf(a[i], bb[j], acc[i][j]);
    }
    #pragma unroll
    for (int i = 0; i < 4; i++) {
        const size_t m = (size_t)b * S_ + d0 + ty * 4 + i;
        const size_t idx = m * F2_ + n0 + tx * 4;
        ushort4 zi = *(const ushort4*)&z1_bf[idx];
        ushort4 o;
        o.x = f2bf(bf2f(zi.x) * acc[i][0]);
        o.y = f2bf(bf2f(zi.y) * acc[i][1]);
        o.z = f2bf(bf2f(zi.z) * acc[i][2]);
        o.w = f2bf(bf2f(zi.w) * acc[i][3]);
        *(ushort4*)&z1_bf[idx] = o;
    }
}

extern "C" void kernel_launch(void* const* d_in, const int* in_sizes, int n_in,
                              void* d_out, int out_size, void* d_ws, size_t ws_size,
                              hipStream_t stream) {
    const float* x     = (const float*)d_in[0];
    const float* Wu    = (const float*)d_in[1];
    const float* bu    = (const float*)d_in[2];
    const float* gamma = (const float*)d_in[3];
    const float* beta  = (const float*)d_in[4];
    const float* Wv    = (const float*)d_in[5];
    const float* bv    = (const float*)d_in[6];
    const float* bases = (const float*)d_in[7];
    float* out = (float*)d_out;

    float* ws = (float*)d_ws;
    const size_t Z   = (size_t)B_ * S_ * F2_;          // 16,777,216
    const size_t NCR = (size_t)B_ * F2_ * R_;          // 1,048,576
    const size_t NBR = (size_t)B_ * S_ * R_;           // 524,288
    const size_t XBF = (size_t)B_ * S_ * F_;           // 8,388,608 u16
    const size_t WUBF = (size_t)FFN_ * F_;             // 4,194,304 u16

    // ---- block A (58.7 MB): [x_bf | Wu_bf | z2_bf], re-used post-LN by [xmT | G | Gp | Wv_bf]
    u16*   x_bf   = (u16*)ws;
    u16*   Wu_bf  = x_bf + XBF;
    u16*   z2_bf  = Wu_bf + WUBF;                     // Z u16; dead after ln_relu
    u16*   xmT_bf = (u16*)ws;                         // alias [0..Z)
    float* G      = (float*)((u16*)ws + Z);           // 8*64*64 floats
    float* Gp     = G + (size_t)B_ * R_ * R_;         // 16*8*64*64 floats (2 MB)
    u16*   Wv_bf  = (u16*)(Gp + (size_t)16 * B_ * R_ * R_);  // 4 MB, written at end
    // ---- persistent region after block A (block A = (Z+XBF+WUBF)/2 floats)
    float* p = ws + (Z + XBF + WUBF) / 2;
    u16*   z1_bf  = (u16*)p;               p += Z / 2;   // z1 / prod (bf16)
    u16*   xm_bf  = (u16*)p;               p += Z / 2;
    float* ncp    = p;                     p += 4 * NCR;
    float* nbp    = p;                     p += 4 * NBR;
    float* bas    = p;                     p += NBR;
    u16*   basT_bf = (u16*)p;              p += NBR / 2;
    float* coef   = p;                     p += NCR;
    u16*   coefT_bf = (u16*)p;             // + NCR/2  (total ~160.4 MB)

    // convert inputs to bf16
    k_cvt_bf16<<<dim3(4096), 256, 0, stream>>>(x,  x_bf,  (int)(XBF / 8));
    k_cvt_bf16<<<dim3(2048), 256, 0, stream>>>(Wu, Wu_bf, (int)(WUBF / 8));

    // front: gated MLP (bf16 MFMA) -> z1_bf + z2_bf
    k_mfma_bt<F_, F2_, true><<<dim3(64, 32), 256, 0, stream>>>(x_bf, Wu_bf, bu, z1_bf, z2_bf, nullptr);
    k_ln_relu<<<dim3(8192), 256, 0, stream>>>(z2_bf, xm_bf, gamma, beta);
    k_transpose_bf<<<dim3(32, 16, B_), 256, 0, stream>>>(xm_bf, xmT_bf);
    k_init_bases<<<dim3(256), 256, 0, stream>>>(bases, bas, basT_bf);

    // init: numer(xm^T bas0) + Gram(bas0); softmax -> coef0
    k_nmf_bt<128, S_, 4, F2_><<<dim3(16, 4, B_), 256, 0, stream>>>(xmT_bf, basT_bf, ncp);
    k_ata_part<<<dim3(16, B_), 256, 0, stream>>>(bas, Gp, S_);
    k_ata_reduce<<<dim3(128), 256, 0, stream>>>(Gp, G);
    k_softmax_coef<<<dim3(4096), 256, 0, stream>>>(ncp, coef, coefT_bf);

    // step 1 coef update: numer & Gram identical to init's (bas unchanged) -> reuse
    k_mult_update<<<dim3(512, B_), 256, 0, stream>>>(coef, ncp, G, F2_, NCR, coefT_bf, F2_);
    k_nmf_bt<64, F2_, 4, S_><<<dim3(16, 4, B_), 256, 0, stream>>>(xm_bf, coefT_bf, nbp);
    k_ata_part<<<dim3(16, B_), 256, 0, stream>>>(coef, Gp, F2_);
    k_ata_reduce<<<dim3(128), 256, 0, stream>>>(Gp, G);
    k_mult_update<<<dim3(256, B_), 256, 0, stream>>>(bas, nbp, G, S_, NBR, basT_bf, S_);

    // steps 2..6
    for (int it = 1; it < NSTEPS; it++) {
        k_nmf_bt<128, S_, 4, F2_><<<dim3(16, 4, B_), 256, 0, stream>>>(xmT_bf, basT_bf, ncp);
        k_ata_part<<<dim3(16, B_), 256, 0, stream>>>(bas, Gp, S_);
        k_ata_reduce<<<dim3(128), 256, 0, stream>>>(Gp, G);
        k_mult_update<<<dim3(512, B_), 256, 0, stream>>>(coef, ncp, G, F2_, NCR, coefT_bf, F2_);
        k_nmf_bt<64, F2_, 4, S_><<<dim3(16, 4, B_), 256, 0, stream>>>(xm_bf, coefT_bf, nbp);
        k_ata_part<<<dim3(16, B_), 256, 0, stream>>>(coef, Gp, F2_);
        k_ata_reduce<<<dim3(128), 256, 0, stream>>>(Gp, G);
        k_mult_update<<<dim3(256, B_), 256, 0, stream>>>(bas, nbp, G, S_, NBR, basT_bf, S_);
    }

    // compute_coef (one more coef update with final bas)
    k_nmf_bt<128, S_, 4, F2_><<<dim3(16, 4, B_), 256, 0, stream>>>(xmT_bf, basT_bf, ncp);
    k_ata_part<<<dim3(16, B_), 256, 0, stream>>>(bas, Gp, S_);
    k_ata_reduce<<<dim3(128), 256, 0, stream>>>(Gp, G);
    k_mult_update<<<dim3(512, B_), 256, 0, stream>>>(coef, ncp, G, F2_, NCR, coefT_bf, F2_);

    // reconstruction + gate, in place on z1_bf -> prod (bf16)
    k_recon_prod<<<dim3(16, 32, B_), 256, 0, stream>>>(bas, coef, z1_bf);

    // convert Wv, then final projection (bf16 MFMA)
    k_cvt_bf16<<<dim3(1024), 256, 0, stream>>>(Wv, Wv_bf, (int)((size_t)F_ * F2_ / 8));
    k_mfma_bt<F2_, F_, false><<<dim3(64, 8), 256, 0, stream>>>(z1_bf, Wv_bf, bv, nullptr, nullptr, out);
}